// Round 17
// baseline (199.704 us; speedup 1.0000x reference)
//
#include <hip/hip_runtime.h>
#include <math.h>

typedef unsigned short ushort_t;
typedef __bf16 bf16x8 __attribute__((ext_vector_type(8)));
typedef float f32x4 __attribute__((ext_vector_type(4)));

// ---------------------------------------------------------------------------
// fp32 <-> bf16 helpers
// ---------------------------------------------------------------------------
__device__ __forceinline__ ushort_t f2b_rne(float f) {
    union { float f; unsigned int u; } c;
    c.f = f;
    unsigned int u = c.u;
    u += 0x7FFFu + ((u >> 16) & 1u);
    return (ushort_t)(u >> 16);
}
__device__ __forceinline__ float b2f(ushort_t v) {
    union { unsigned int u; float f; } c;
    c.u = ((unsigned int)v) << 16;
    return c.f;
}

// async global->LDS DMA, 16B per lane.
__device__ __forceinline__ void gl_lds16(const ushort_t* g, ushort_t* l) {
    __builtin_amdgcn_global_load_lds(
        (const __attribute__((address_space(1))) void*)g,
        (__attribute__((address_space(3))) void*)l, 16, 0, 0);
}

// ---------------------------------------------------------------------------
// prep: bf16 conversions + zero LN colsum accumulators + ZERO d_out
// (attn_split accumulates into out via atomicAdd; harness poisons, not zeros).
// ---------------------------------------------------------------------------
__global__ __launch_bounds__(256) void prep(
    const float* __restrict__ x, const float* __restrict__ context,
    const float* __restrict__ Wq, const float* __restrict__ Wk,
    const float* __restrict__ Wv1, const float* __restrict__ Wout,
    ushort_t* __restrict__ x_b, ushort_t* __restrict__ ctx_b,
    ushort_t* __restrict__ Wq_t, ushort_t* __restrict__ Wk_t,
    ushort_t* __restrict__ Wv1_t, ushort_t* __restrict__ Wout_b,
    float* __restrict__ colzero,   // colsum|colsumsq, 2*Mn floats
    float* __restrict__ outz,      // d_out, M*768 floats
    int b, int n) {
    const int t = threadIdx.x;
    const int bid = blockIdx.x;
    const int nb_x = (b * 64 * 768 / 4) / 256;
    const int nb_c = (b * n * 768 / 4) / 256;

    if (bid < nb_x + nb_c) {  // flat converts (x, context)
        const float* in = (bid < nb_x) ? x : context;
        ushort_t* outp = (bid < nb_x) ? x_b : ctx_b;
        const int i = ((bid < nb_x) ? bid : (bid - nb_x)) * 256 + t;
        float4 v = ((const float4*)in)[i];
        ushort_t o[4] = {f2b_rne(v.x), f2b_rne(v.y), f2b_rne(v.z), f2b_rne(v.w)};
        *(uint2*)&outp[(size_t)i * 4] = *(uint2*)o;
        return;
    }

    int u = bid - nb_x - nb_c;
    if (u >= 4808) {  // zero d_out: 192 blocks x 256 x float4
        const int idx = (u - 4808) * 256 + t;
        ((float4*)outz)[idx] = make_float4(0.f, 0.f, 0.f, 0.f);
        return;
    }
    if (u >= 4800) {  // zero colsum/colsumsq: 8 blocks x 256 x float4
        const int idx = (u - 4800) * 256 + t;
        ((float4*)colzero)[idx] = make_float4(0.f, 0.f, 0.f, 0.f);
        return;
    }
    if (u >= 4224) {  // Wout flat convert: 576 blocks x 1024 floats
        const int i = (u - 4224) * 256 + t;
        float4 v = ((const float4*)Wout)[i];
        ushort_t o[4] = {f2b_rne(v.x), f2b_rne(v.y), f2b_rne(v.z), f2b_rne(v.w)};
        *(uint2*)&Wout_b[(size_t)i * 4] = *(uint2*)o;
        return;
    }

    // transposes: Wq 576, Wk 576, Wv1 3072
    const float* in;
    ushort_t* outp;
    int R = 768, C = 768;
    if (u < 576)        { in = Wq;  outp = Wq_t; }
    else if (u < 1152)  { u -= 576;  in = Wk;  outp = Wk_t; }
    else                { u -= 1152; in = Wv1; outp = Wv1_t; C = 4096; }
    const int ct = C / 32;
    const int c0 = (u % ct) * 32, r0 = (u / ct) * 32;
    const int tx = t & 31, ty = t >> 5;

    __shared__ float tt[32][33];
#pragma unroll
    for (int i = 0; i < 4; i++)
        tt[ty + 8 * i][tx] = in[(size_t)(r0 + ty + 8 * i) * C + c0 + tx];
    __syncthreads();
#pragma unroll
    for (int i = 0; i < 4; i++)
        outp[(size_t)(c0 + ty + 8 * i) * R + r0 + tx] = f2b_rne(tt[tx][ty + 8 * i]);
}

// ---------------------------------------------------------------------------
// gemm3: q, k GEMMs + h1^T GEMM via tile list. BK=64 as two stacked 32-slabs
// (proven R16 structure: 8 DMA + 32 MFMA per barrier pair, 12 K-iters).
// ---------------------------------------------------------------------------
__global__ __launch_bounds__(256) void gemm3(
    const ushort_t* __restrict__ x_b, const ushort_t* __restrict__ ctx_b,
    const ushort_t* __restrict__ Wq_t, const ushort_t* __restrict__ Wk_t,
    const ushort_t* __restrict__ Wv1_t,
    ushort_t* __restrict__ qb, ushort_t* __restrict__ kb,
    ushort_t* __restrict__ h1t, int b, int n) {
    const int bid = blockIdx.x;
    const int tq = (b * 64 / 128) * 6;
    const int tk = (b * n / 128) * 6;
    const int Mn = b * n;

    const ushort_t *A, *Bt;
    ushort_t* C;
    int N, row0, col0;
    if (bid < tq) {
        A = x_b; Bt = Wq_t; C = qb; N = 768;
        row0 = (bid / 6) * 128; col0 = (bid % 6) * 128;
    } else if (bid < tq + tk) {
        const int u = bid - tq;
        A = ctx_b; Bt = Wk_t; C = kb; N = 768;
        row0 = (u / 6) * 128; col0 = (u % 6) * 128;
    } else {
        const int u = bid - tq - tk;
        A = Wv1_t; Bt = ctx_b; C = h1t; N = Mn;
        row0 = (u % 32) * 128; col0 = (u / 32) * 128;
    }
    const int K = 768;

    __shared__ ushort_t As[2 * 128 * 32];
    __shared__ ushort_t Bs[2 * 128 * 32];

    const int t = threadIdx.x;
    const int lane = t & 63;
    const int wave = t >> 6;
    const int quad = lane >> 4;
    const int l15 = lane & 15;
    const int wm = (wave >> 1) * 64;
    const int wn = (wave & 1) * 64;

    const ushort_t* gA0 = A + (size_t)(row0 + (t >> 2)) * K + (t & 3) * 8;
    const ushort_t* gA1 = gA0 + (size_t)64 * K;
    const ushort_t* gB0 = Bt + (size_t)(col0 + (t >> 2)) * K + (t & 3) * 8;
    const ushort_t* gB1 = gB0 + (size_t)64 * K;

    ushort_t* lA0 = &As[wave * 512];
    ushort_t* lA1 = &As[2048 + wave * 512];
    ushort_t* lA2 = &As[4096 + wave * 512];
    ushort_t* lA3 = &As[6144 + wave * 512];
    ushort_t* lB0 = &Bs[wave * 512];
    ushort_t* lB1 = &Bs[2048 + wave * 512];
    ushort_t* lB2 = &Bs[4096 + wave * 512];
    ushort_t* lB3 = &Bs[6144 + wave * 512];

    f32x4 acc[4][4] = {};

    for (int k0 = 0; k0 < K; k0 += 64) {
        __syncthreads();
        gl_lds16(gA0 + k0, lA0);
        gl_lds16(gA1 + k0, lA1);
        gl_lds16(gA0 + k0 + 32, lA2);
        gl_lds16(gA1 + k0 + 32, lA3);
        gl_lds16(gB0 + k0, lB0);
        gl_lds16(gB1 + k0, lB1);
        gl_lds16(gB0 + k0 + 32, lB2);
        gl_lds16(gB1 + k0 + 32, lB3);
        __syncthreads();

#pragma unroll
        for (int ks = 0; ks < 2; ks++) {
            bf16x8 af[4], bfr[4];
#pragma unroll
            for (int i = 0; i < 4; i++)
                af[i] = *(const bf16x8*)&As[ks * 4096 + (wm + i * 16 + l15) * 32 + quad * 8];
#pragma unroll
            for (int j = 0; j < 4; j++)
                bfr[j] = *(const bf16x8*)&Bs[ks * 4096 + (wn + j * 16 + l15) * 32 + quad * 8];
#pragma unroll
            for (int i = 0; i < 4; i++)
#pragma unroll
                for (int j = 0; j < 4; j++)
                    acc[i][j] = __builtin_amdgcn_mfma_f32_16x16x32_bf16(
                        af[i], bfr[j], acc[i][j], 0, 0, 0);
        }
    }

#pragma unroll
    for (int i = 0; i < 4; i++)
#pragma unroll
        for (int j = 0; j < 4; j++)
#pragma unroll
            for (int r = 0; r < 4; r++) {
                const int row = row0 + wm + i * 16 + quad * 4 + r;
                const int col = col0 + wn + j * 16 + l15;
                C[(size_t)row * N + col] = f2b_rne(acc[i][j][r]);
            }
}

// ---------------------------------------------------------------------------
// scores_stats: region 0 (b*8*(n/128)): S = QK^T/sqrt(96).
// region 1 (256 blocks): LN col sums of h1t, 256x256 panels, bf16x8 loads.
// ---------------------------------------------------------------------------
__global__ __launch_bounds__(256) void scores_stats(
    const ushort_t* __restrict__ qb, const ushort_t* __restrict__ kb,
    const ushort_t* __restrict__ h1t, float* __restrict__ S,
    float* __restrict__ colsum, float* __restrict__ colsumsq,
    int b, int n, int Mn) {
    __shared__ ushort_t sb[192 * 104];
    const int t = threadIdx.x;
    const int nsc = b * 8 * (n / 128);

    if (blockIdx.x >= nsc) {  // ---- LN column-sum panel ----
        const int u = blockIdx.x - nsc;
        const int rc = u >> 4;
        const int cc = u & 15;
        const int cg = t & 31;
        const int rg = t >> 5;
        const ushort_t* p =
            h1t + (size_t)(rc * 256 + rg * 32) * Mn + cc * 256 + cg * 8;
        float s[8] = {}, s2[8] = {};
#pragma unroll 4
        for (int r = 0; r < 32; r++) {
            const bf16x8 v = *(const bf16x8*)&p[(size_t)r * Mn];
#pragma unroll
            for (int j = 0; j < 8; j++) {
                const float f = (float)v[j];
                s[j] += f;
                s2[j] += f * f;
            }
        }
        float* red = (float*)sb;
#pragma unroll
        for (int j = 0; j < 8; j++) {
            red[rg * 256 + cg * 8 + j] = s[j];
            red[2048 + rg * 256 + cg * 8 + j] = s2[j];
        }
        __syncthreads();
        float ts = 0.f, ts2 = 0.f;
#pragma unroll
        for (int g = 0; g < 8; g++) {
            ts += red[g * 256 + t];
            ts2 += red[2048 + g * 256 + t];
        }
        atomicAdd(&colsum[cc * 256 + t], ts);
        atomicAdd(&colsumsq[cc * 256 + t], ts2);
        return;
    }

    // ---- scores tile ----
    const int nt = n / 128;
    const int n0 = (blockIdx.x % nt) * 128;
    const int bh = blockIdx.x / nt;
    const int bb = bh >> 3, h = bh & 7;
    const int lane = t & 63, wave = t >> 6;
    const int quad = lane >> 4, l15 = lane & 15;
    const int wm = (wave >> 1) * 32;
    const int wn = (wave & 1) * 64;

    ushort_t* Qs = sb;
    ushort_t* Ks = sb + 64 * 104;

    for (int g = t; g < 768; g += 256) {
        const int r = g / 12, s = g - r * 12;
        *(bf16x8*)&Qs[r * 104 + s * 8] =
            *(const bf16x8*)&qb[(size_t)(bb * 64 + r) * 768 + h * 96 + s * 8];
    }
    for (int g = t; g < 1536; g += 256) {
        const int r = g / 12, s = g - r * 12;
        *(bf16x8*)&Ks[r * 104 + s * 8] =
            *(const bf16x8*)&kb[(size_t)(bb * n + n0 + r) * 768 + h * 96 + s * 8];
    }
    __syncthreads();

    f32x4 acc[2][4] = {};
#pragma unroll
    for (int ks = 0; ks < 3; ks++) {
        bf16x8 af[2], bfr[4];
#pragma unroll
        for (int i = 0; i < 2; i++)
            af[i] = *(const bf16x8*)&Qs[(wm + i * 16 + l15) * 104 + ks * 32 + quad * 8];
#pragma unroll
        for (int j = 0; j < 4; j++)
            bfr[j] = *(const bf16x8*)&Ks[(wn + j * 16 + l15) * 104 + ks * 32 + quad * 8];
#pragma unroll
        for (int i = 0; i < 2; i++)
#pragma unroll
            for (int j = 0; j < 4; j++)
                acc[i][j] = __builtin_amdgcn_mfma_f32_16x16x32_bf16(
                    af[i], bfr[j], acc[i][j], 0, 0, 0);
    }

    const float sc = 0.10206207261596575f;  // 1/sqrt(96)
    float* Sp = S + (size_t)bh * 64 * n;
#pragma unroll
    for (int i = 0; i < 2; i++)
#pragma unroll
        for (int j = 0; j < 4; j++)
#pragma unroll
            for (int r = 0; r < 4; r++) {
                const int row = wm + i * 16 + quad * 4 + r;
                const int col = n0 + wn + j * 16 + l15;
                Sp[(size_t)row * n + col] = acc[i][j][r] * sc;
            }
}

// ---------------------------------------------------------------------------
// attn_split (512 thr / 8 waves): one block per (head-pair a, bq).
// Heads h0=2a, h0+1. Softmax: 4 waves per head over quarter-n, LDS-merged.
// PV MFMA: waves 0..3 own one 16-col j-block; A rows = {w[h0], w[h1], 0...}.
// LN affine + Wc for the block's 192-wide d-slice -> sO; partial Wout matvec
// (192-deep) atomicAdd'ed into out (zeroed by prep). 1024 blocks => ~3-4/CU.
// ---------------------------------------------------------------------------
__global__ __launch_bounds__(512) void attn_split(
    const float* __restrict__ S, const float* __restrict__ colsum,
    const float* __restrict__ colsumsq, const ushort_t* __restrict__ h1t,
    const float* __restrict__ ln_g, const float* __restrict__ ln_b,
    const float* __restrict__ Wc, const ushort_t* __restrict__ Wout_b,
    float* __restrict__ out, int n, int Mn) {
    const int a = blockIdx.x;           // head-pair 0..3
    const int bq = blockIdx.y;
    const int bb = bq >> 6, qi = bq & 63;
    const int tid = threadIdx.x;
    const int lane = tid & 63, wv = tid >> 6;   // wv 0..7
    const int quad = lane >> 4, l15 = lane & 15;
    const int h0 = a * 2;

    __shared__ ushort_t sW[3 * 1032];   // rows: w[h0], w[h0+1], zeros
    __shared__ ushort_t sH[64 * 264];   // H chunk; overlay mu/rstd before PV
    __shared__ float pm[8], pl[8], pwm[8];
    __shared__ float sl[2], swmu[2];
    __shared__ float sA[2 * 64];
    __shared__ float sO[192];

    float* sMu = (float*)sH;            // [1024]
    float* sRs = (float*)sH + 1024;     // [1024]

    // LN stats from column sums
    for (int i = tid; i < n; i += 512) {
        const float cs = colsum[bb * n + i];
        const float cq = colsumsq[bb * n + i];
        const float m = cs * (1.0f / 4096.0f);
        sMu[i] = m;
        sRs[i] = rsqrtf(cq * (1.0f / 4096.0f) - m * m + 1e-5f);
    }
    for (int i = tid; i < 1032; i += 512) sW[2 * 1032 + i] = 0;  // zero row
    __syncthreads();

    // softmax: wave wv -> local head hl = wv>>2, quarter qt = wv&3
    const int hl = wv >> 2;
    const int qt = wv & 3;
    const int nq4 = n >> 2;
    const int i0 = qt * nq4;
    const float* Sp = S + ((size_t)(bb * 8 + h0 + hl) * 64 + qi) * n;
    {
        float m = -1e30f;
        for (int i = i0 + lane; i < i0 + nq4; i += 64) m = fmaxf(m, Sp[i]);
#pragma unroll
        for (int off = 32; off > 0; off >>= 1) m = fmaxf(m, __shfl_down(m, off));
        if (lane == 0) pm[wv] = m;
    }
    __syncthreads();
    const float mh = fmaxf(fmaxf(pm[hl * 4], pm[hl * 4 + 1]),
                           fmaxf(pm[hl * 4 + 2], pm[hl * 4 + 3]));
    {
        float l = 0.f, wm = 0.f;
        for (int i = i0 + lane; i < i0 + nq4; i += 64) {
            const float e = expf(Sp[i] - mh);
            const float w = e * sRs[i];
            const ushort_t wb = f2b_rne(w);
            sW[hl * 1032 + i] = wb;
            l += e;
            wm += b2f(wb) * sMu[i];
        }
#pragma unroll
        for (int off = 32; off > 0; off >>= 1) {
            l += __shfl_down(l, off);
            wm += __shfl_down(wm, off);
        }
        if (lane == 0) { pl[wv] = l; pwm[wv] = wm; }
    }
    __syncthreads();
    if (tid < 2) {
        sl[tid] = pl[tid * 4] + pl[tid * 4 + 1] + pl[tid * 4 + 2] + pl[tid * 4 + 3];
        swmu[tid] = pwm[tid * 4] + pwm[tid * 4 + 1] + pwm[tid * 4 + 2] + pwm[tid * 4 + 3];
    }

    // PV via MFMA: C rows 0,1 = heads h0,h0+1. A rows: l15 0/1 -> w, else zero.
    const int mrow = (l15 < 2 ? l15 : 2) * 1032;
    f32x4 acc = {};
    const int nch = n >> 8;
    for (int ch = 0; ch < nch; ch++) {
        __syncthreads();  // chunk0: protects sMu/sRs overlay + sW/sl writes
        for (int g = tid; g < 2048; g += 512) {
            const int row = g >> 5, seg = g & 31;
            *(bf16x8*)&sH[row * 264 + seg * 8] =
                *(const bf16x8*)&h1t[(size_t)(qi * 64 + row) * Mn + bb * n +
                                     ch * 256 + seg * 8];
        }
        __syncthreads();
        if (wv < 4) {
#pragma unroll
            for (int ks = 0; ks < 8; ks++) {
                const bf16x8 af = *(const bf16x8*)&sW[mrow + ch * 256 + ks * 32 + quad * 8];
                const bf16x8 bf = *(const bf16x8*)&sH[(wv * 16 + l15) * 264 + ks * 32 + quad * 8];
                acc = __builtin_amdgcn_mfma_f32_16x16x32_bf16(af, bf, acc, 0, 0, 0);
            }
        }
    }
    __syncthreads();

    // epilogue: C row = quad*4 + r -> rows 0,1 live in quad 0, r 0/1.
    if (wv < 4 && quad == 0) {
#pragma unroll
        for (int r = 0; r < 2; r++) {
            const int rr = wv * 16 + l15;      // rank index 0..63
            const int c = qi * 64 + rr;
            sA[r * 64 + rr] = ln_g[c] * ((acc[r] - swmu[r]) / sl[r]) + ln_b[c];
        }
    }
    __syncthreads();

    // Wc apply for this block's d-slice [a*192, a*192+192)
    if (tid < 192) {
        const int dg = a * 192 + tid;
        const int hl2 = tid / 96;              // local head 0/1
        const float* wp = Wc + (size_t)qi * 49152 + dg;
        float acc2 = 0.f;
#pragma unroll
        for (int r = 0; r < 64; r++) acc2 += sA[hl2 * 64 + r] * wp[(size_t)r * 768];
        sO[tid] = b2f(f2b_rne(acc2));
    }
    __syncthreads();

    // Partial Wout matvec: out[bq][dout] += sum_{dl} sO[dl]*Wout_b[a*192+dl][dout]
    for (int dout = tid; dout < 768; dout += 512) {
        const float4* sO4 = (const float4*)sO;  // 48 x float4
        float a0 = 0.f, a1 = 0.f, a2 = 0.f, a3 = 0.f;
#pragma unroll 4
        for (int d4 = 0; d4 < 48; d4++) {
            const float4 s4 = sO4[d4];
            const int d = a * 192 + d4 * 4;
            a0 += s4.x * b2f(Wout_b[(size_t)d * 768 + dout]);
            a1 += s4.y * b2f(Wout_b[(size_t)(d + 1) * 768 + dout]);
            a2 += s4.z * b2f(Wout_b[(size_t)(d + 2) * 768 + dout]);
            a3 += s4.w * b2f(Wout_b[(size_t)(d + 3) * 768 + dout]);
        }
        atomicAdd(&out[(size_t)bq * 768 + dout], (a0 + a1) + (a2 + a3));
    }
}

// ---------------------------------------------------------------------------
extern "C" void kernel_launch(void* const* d_in, const int* in_sizes, int n_in,
                              void* d_out, int out_size, void* d_ws, size_t ws_size,
                              hipStream_t stream) {
    const float* x       = (const float*)d_in[0];
    const float* context = (const float*)d_in[1];
    const float* Wq      = (const float*)d_in[2];
    const float* Wk      = (const float*)d_in[3];
    const float* Wv1     = (const float*)d_in[4];
    const float* ln_g    = (const float*)d_in[5];
    const float* ln_b    = (const float*)d_in[6];
    const float* Wc      = (const float*)d_in[7];
    const float* Wout    = (const float*)d_in[8];
    float* out = (float*)d_out;

    const int b = in_sizes[0] / (64 * 768);
    const int n = in_sizes[1] / (b * 768);
    const int M  = b * 64;     // 256
    const int Mn = b * n;      // 4096

    float* ws = (float*)d_ws;
    size_t off = 0;
    float* S       = ws + off;  off += (size_t)b * 8 * 64 * n;
    float* colsum  = ws + off;  off += (size_t)Mn;
    float* colsumsq= ws + off;  off += (size_t)Mn;

    ushort_t* us = (ushort_t*)(ws + off);
    size_t uo = 0;
    ushort_t* x_b    = us + uo;  uo += (size_t)M * 768;
    ushort_t* ctx_b  = us + uo;  uo += (size_t)Mn * 768;
    ushort_t* qb     = us + uo;  uo += (size_t)M * 768;
    ushort_t* kb     = us + uo;  uo += (size_t)Mn * 768;
    ushort_t* h1t    = us + uo;  uo += (size_t)Mn * 4096;   // [c][n_glob]
    ushort_t* Wq_t   = us + uo;  uo += (size_t)768 * 768;
    ushort_t* Wk_t   = us + uo;  uo += (size_t)768 * 768;
    ushort_t* Wv1_t  = us + uo;  uo += (size_t)4096 * 768;
    ushort_t* Wout_b = us + uo;  uo += (size_t)768 * 768;

    // 1. conversions + zero LN accumulators + zero d_out
    const int nb_x = (M * 768 / 4) / 256;
    const int nb_c = (Mn * 768 / 4) / 256;
    const int nb_oz = (M * 768 / 4) / 256;   // 192
    prep<<<nb_x + nb_c + 4800 + 8 + nb_oz, 256, 0, stream>>>(
        x, context, Wq, Wk, Wv1, Wout, x_b, ctx_b, Wq_t, Wk_t, Wv1_t, Wout_b,
        colsum, out, b, n);

    // 2. q, k, h1^T GEMMs (BK=64, two stacked 32-slabs)
    const int tq = (M / 128) * 6, tk = (Mn / 128) * 6;
    const int th = (4096 / 128) * (Mn / 128);
    gemm3<<<tq + tk + th, 256, 0, stream>>>(x_b, ctx_b, Wq_t, Wk_t, Wv1_t,
                                            qb, kb, h1t, b, n);

    // 3. scores + LN column sums
    scores_stats<<<b * 8 * (n / 128) + 256, 256, 0, stream>>>(
        qb, kb, h1t, S, colsum, colsumsq, b, n, Mn);

    // 4. split attention: (head-pair, bq) grid, partial Wout via atomicAdd
    attn_split<<<dim3(4, M), 512, 0, stream>>>(S, colsum, colsumsq, h1t,
                                               ln_g, ln_b, Wc, Wout_b, out, n, Mn);
}

// Round 18
// 169.741 us; speedup vs baseline: 1.1765x; 1.1765x over previous
//
#include <hip/hip_runtime.h>
#include <math.h>

typedef unsigned short ushort_t;
typedef __bf16 bf16x8 __attribute__((ext_vector_type(8)));
typedef float f32x4 __attribute__((ext_vector_type(4)));

// ---------------------------------------------------------------------------
// fp32 <-> bf16 helpers
// ---------------------------------------------------------------------------
__device__ __forceinline__ ushort_t f2b_rne(float f) {
    union { float f; unsigned int u; } c;
    c.f = f;
    unsigned int u = c.u;
    u += 0x7FFFu + ((u >> 16) & 1u);
    return (ushort_t)(u >> 16);
}
__device__ __forceinline__ float b2f(ushort_t v) {
    union { unsigned int u; float f; } c;
    c.u = ((unsigned int)v) << 16;
    return c.f;
}

// async global->LDS DMA, 16B per lane.
__device__ __forceinline__ void gl_lds16(const ushort_t* g, ushort_t* l) {
    __builtin_amdgcn_global_load_lds(
        (const __attribute__((address_space(1))) void*)g,
        (__attribute__((address_space(3))) void*)l, 16, 0, 0);
}

// ---------------------------------------------------------------------------
// prep: all bf16 conversions + zeroing of LN colsum accumulators.
// Wout flat-converted (no transpose): Wout_b[d][dout] for the fused matvec.
// ---------------------------------------------------------------------------
__global__ __launch_bounds__(256) void prep(
    const float* __restrict__ x, const float* __restrict__ context,
    const float* __restrict__ Wq, const float* __restrict__ Wk,
    const float* __restrict__ Wv1, const float* __restrict__ Wout,
    ushort_t* __restrict__ x_b, ushort_t* __restrict__ ctx_b,
    ushort_t* __restrict__ Wq_t, ushort_t* __restrict__ Wk_t,
    ushort_t* __restrict__ Wv1_t, ushort_t* __restrict__ Wout_b,
    float* __restrict__ colzero,   // colsum|colsumsq, 2*Mn floats
    int b, int n) {
    const int t = threadIdx.x;
    const int bid = blockIdx.x;
    const int nb_x = (b * 64 * 768 / 4) / 256;
    const int nb_c = (b * n * 768 / 4) / 256;

    if (bid < nb_x + nb_c) {  // flat converts (x, context)
        const float* in = (bid < nb_x) ? x : context;
        ushort_t* outp = (bid < nb_x) ? x_b : ctx_b;
        const int i = ((bid < nb_x) ? bid : (bid - nb_x)) * 256 + t;
        float4 v = ((const float4*)in)[i];
        ushort_t o[4] = {f2b_rne(v.x), f2b_rne(v.y), f2b_rne(v.z), f2b_rne(v.w)};
        *(uint2*)&outp[(size_t)i * 4] = *(uint2*)o;
        return;
    }

    int u = bid - nb_x - nb_c;
    if (u >= 4800) {  // zero colsum/colsumsq: 8 blocks x 256 x float4
        const int idx = (u - 4800) * 256 + t;
        ((float4*)colzero)[idx] = make_float4(0.f, 0.f, 0.f, 0.f);
        return;
    }
    if (u >= 4224) {  // Wout flat convert: 576 blocks x 1024 floats
        const int i = (u - 4224) * 256 + t;
        float4 v = ((const float4*)Wout)[i];
        ushort_t o[4] = {f2b_rne(v.x), f2b_rne(v.y), f2b_rne(v.z), f2b_rne(v.w)};
        *(uint2*)&Wout_b[(size_t)i * 4] = *(uint2*)o;
        return;
    }

    // transposes: Wq 576, Wk 576, Wv1 3072
    const float* in;
    ushort_t* outp;
    int R = 768, C = 768;
    if (u < 576)        { in = Wq;  outp = Wq_t; }
    else if (u < 1152)  { u -= 576;  in = Wk;  outp = Wk_t; }
    else                { u -= 1152; in = Wv1; outp = Wv1_t; C = 4096; }
    const int ct = C / 32;
    const int c0 = (u % ct) * 32, r0 = (u / ct) * 32;
    const int tx = t & 31, ty = t >> 5;

    __shared__ float tt[32][33];
#pragma unroll
    for (int i = 0; i < 4; i++)
        tt[ty + 8 * i][tx] = in[(size_t)(r0 + ty + 8 * i) * C + c0 + tx];
    __syncthreads();
#pragma unroll
    for (int i = 0; i < 4; i++)
        outp[(size_t)(c0 + ty + 8 * i) * R + r0 + tx] = f2b_rne(tt[tx][ty + 8 * i]);
}

// ---------------------------------------------------------------------------
// gemm3: q, k GEMMs + h1^T GEMM via tile list. BK=64 as two stacked 32-slabs
// (R16 structure: 8 DMA + 32 MFMA per barrier pair, 12 K-iters).
// ---------------------------------------------------------------------------
__global__ __launch_bounds__(256) void gemm3(
    const ushort_t* __restrict__ x_b, const ushort_t* __restrict__ ctx_b,
    const ushort_t* __restrict__ Wq_t, const ushort_t* __restrict__ Wk_t,
    const ushort_t* __restrict__ Wv1_t,
    ushort_t* __restrict__ qb, ushort_t* __restrict__ kb,
    ushort_t* __restrict__ h1t, int b, int n) {
    const int bid = blockIdx.x;
    const int tq = (b * 64 / 128) * 6;
    const int tk = (b * n / 128) * 6;
    const int Mn = b * n;

    const ushort_t *A, *Bt;
    ushort_t* C;
    int N, row0, col0;
    if (bid < tq) {
        A = x_b; Bt = Wq_t; C = qb; N = 768;
        row0 = (bid / 6) * 128; col0 = (bid % 6) * 128;
    } else if (bid < tq + tk) {
        const int u = bid - tq;
        A = ctx_b; Bt = Wk_t; C = kb; N = 768;
        row0 = (u / 6) * 128; col0 = (u % 6) * 128;
    } else {
        const int u = bid - tq - tk;
        A = Wv1_t; Bt = ctx_b; C = h1t; N = Mn;
        row0 = (u % 32) * 128; col0 = (u / 32) * 128;
    }
    const int K = 768;

    __shared__ ushort_t As[2 * 128 * 32];
    __shared__ ushort_t Bs[2 * 128 * 32];

    const int t = threadIdx.x;
    const int lane = t & 63;
    const int wave = t >> 6;
    const int quad = lane >> 4;
    const int l15 = lane & 15;
    const int wm = (wave >> 1) * 64;
    const int wn = (wave & 1) * 64;

    const ushort_t* gA0 = A + (size_t)(row0 + (t >> 2)) * K + (t & 3) * 8;
    const ushort_t* gA1 = gA0 + (size_t)64 * K;
    const ushort_t* gB0 = Bt + (size_t)(col0 + (t >> 2)) * K + (t & 3) * 8;
    const ushort_t* gB1 = gB0 + (size_t)64 * K;

    ushort_t* lA0 = &As[wave * 512];
    ushort_t* lA1 = &As[2048 + wave * 512];
    ushort_t* lA2 = &As[4096 + wave * 512];
    ushort_t* lA3 = &As[6144 + wave * 512];
    ushort_t* lB0 = &Bs[wave * 512];
    ushort_t* lB1 = &Bs[2048 + wave * 512];
    ushort_t* lB2 = &Bs[4096 + wave * 512];
    ushort_t* lB3 = &Bs[6144 + wave * 512];

    f32x4 acc[4][4] = {};

    for (int k0 = 0; k0 < K; k0 += 64) {
        __syncthreads();
        gl_lds16(gA0 + k0, lA0);
        gl_lds16(gA1 + k0, lA1);
        gl_lds16(gA0 + k0 + 32, lA2);
        gl_lds16(gA1 + k0 + 32, lA3);
        gl_lds16(gB0 + k0, lB0);
        gl_lds16(gB1 + k0, lB1);
        gl_lds16(gB0 + k0 + 32, lB2);
        gl_lds16(gB1 + k0 + 32, lB3);
        __syncthreads();

#pragma unroll
        for (int ks = 0; ks < 2; ks++) {
            bf16x8 af[4], bfr[4];
#pragma unroll
            for (int i = 0; i < 4; i++)
                af[i] = *(const bf16x8*)&As[ks * 4096 + (wm + i * 16 + l15) * 32 + quad * 8];
#pragma unroll
            for (int j = 0; j < 4; j++)
                bfr[j] = *(const bf16x8*)&Bs[ks * 4096 + (wn + j * 16 + l15) * 32 + quad * 8];
#pragma unroll
            for (int i = 0; i < 4; i++)
#pragma unroll
                for (int j = 0; j < 4; j++)
                    acc[i][j] = __builtin_amdgcn_mfma_f32_16x16x32_bf16(
                        af[i], bfr[j], acc[i][j], 0, 0, 0);
        }
    }

    // C/D layout: col = lane&15, row = quad*4 + reg   [m89/m91]
#pragma unroll
    for (int i = 0; i < 4; i++)
#pragma unroll
        for (int j = 0; j < 4; j++)
#pragma unroll
            for (int r = 0; r < 4; r++) {
                const int row = row0 + wm + i * 16 + quad * 4 + r;
                const int col = col0 + wn + j * 16 + l15;
                C[(size_t)row * N + col] = f2b_rne(acc[i][j][r]);
            }
}

// ---------------------------------------------------------------------------
// scores_stats: region 0 (b*8*(n/128)): S = QK^T/sqrt(96).
// region 1 (256 blocks): LN col sums of h1t, 256x256 panels, bf16x8 loads.
// ---------------------------------------------------------------------------
__global__ __launch_bounds__(256) void scores_stats(
    const ushort_t* __restrict__ qb, const ushort_t* __restrict__ kb,
    const ushort_t* __restrict__ h1t, float* __restrict__ S,
    float* __restrict__ colsum, float* __restrict__ colsumsq,
    int b, int n, int Mn) {
    __shared__ ushort_t sb[192 * 104];
    const int t = threadIdx.x;
    const int nsc = b * 8 * (n / 128);

    if (blockIdx.x >= nsc) {  // ---- LN column-sum panel ----
        const int u = blockIdx.x - nsc;
        const int rc = u >> 4;
        const int cc = u & 15;
        const int cg = t & 31;
        const int rg = t >> 5;
        const ushort_t* p =
            h1t + (size_t)(rc * 256 + rg * 32) * Mn + cc * 256 + cg * 8;
        float s[8] = {}, s2[8] = {};
#pragma unroll 4
        for (int r = 0; r < 32; r++) {
            const bf16x8 v = *(const bf16x8*)&p[(size_t)r * Mn];
#pragma unroll
            for (int j = 0; j < 8; j++) {
                const float f = (float)v[j];
                s[j] += f;
                s2[j] += f * f;
            }
        }
        float* red = (float*)sb;
#pragma unroll
        for (int j = 0; j < 8; j++) {
            red[rg * 256 + cg * 8 + j] = s[j];
            red[2048 + rg * 256 + cg * 8 + j] = s2[j];
        }
        __syncthreads();
        float ts = 0.f, ts2 = 0.f;
#pragma unroll
        for (int g = 0; g < 8; g++) {
            ts += red[g * 256 + t];
            ts2 += red[2048 + g * 256 + t];
        }
        atomicAdd(&colsum[cc * 256 + t], ts);
        atomicAdd(&colsumsq[cc * 256 + t], ts2);
        return;
    }

    // ---- scores tile ----
    const int nt = n / 128;
    const int n0 = (blockIdx.x % nt) * 128;
    const int bh = blockIdx.x / nt;
    const int bb = bh >> 3, h = bh & 7;
    const int lane = t & 63, wave = t >> 6;
    const int quad = lane >> 4, l15 = lane & 15;
    const int wm = (wave >> 1) * 32;
    const int wn = (wave & 1) * 64;

    ushort_t* Qs = sb;
    ushort_t* Ks = sb + 64 * 104;

    for (int g = t; g < 768; g += 256) {
        const int r = g / 12, s = g - r * 12;
        *(bf16x8*)&Qs[r * 104 + s * 8] =
            *(const bf16x8*)&qb[(size_t)(bb * 64 + r) * 768 + h * 96 + s * 8];
    }
    for (int g = t; g < 1536; g += 256) {
        const int r = g / 12, s = g - r * 12;
        *(bf16x8*)&Ks[r * 104 + s * 8] =
            *(const bf16x8*)&kb[(size_t)(bb * n + n0 + r) * 768 + h * 96 + s * 8];
    }
    __syncthreads();

    f32x4 acc[2][4] = {};
#pragma unroll
    for (int ks = 0; ks < 3; ks++) {
        bf16x8 af[2], bfr[4];
#pragma unroll
        for (int i = 0; i < 2; i++)
            af[i] = *(const bf16x8*)&Qs[(wm + i * 16 + l15) * 104 + ks * 32 + quad * 8];
#pragma unroll
        for (int j = 0; j < 4; j++)
            bfr[j] = *(const bf16x8*)&Ks[(wn + j * 16 + l15) * 104 + ks * 32 + quad * 8];
#pragma unroll
        for (int i = 0; i < 2; i++)
#pragma unroll
            for (int j = 0; j < 4; j++)
                acc[i][j] = __builtin_amdgcn_mfma_f32_16x16x32_bf16(
                    af[i], bfr[j], acc[i][j], 0, 0, 0);
    }

    const float sc = 0.10206207261596575f;  // 1/sqrt(96)
    float* Sp = S + (size_t)bh * 64 * n;
#pragma unroll
    for (int i = 0; i < 2; i++)
#pragma unroll
        for (int j = 0; j < 4; j++)
#pragma unroll
            for (int r = 0; r < 4; r++) {
                const int row = wm + i * 16 + quad * 4 + r;
                const int col = n0 + wn + j * 16 + l15;
                Sp[(size_t)row * n + col] = acc[i][j][r] * sc;
            }
}

// ---------------------------------------------------------------------------
// attn_fused (1024 thr / 16 waves): one block per (b,qi).
// - softmax: 2 waves per head over half of n each; partials merged in LDS.
// - PV MFMA: waves 0..3 each own one 16-col j-block (no redundancy).
// - LN affine + Wc apply -> sO row (bf16-rounded) in LDS.
// - Wout matvec (ROW-GROUPED, R18): 768 threads in 8 row-groups of 96;
//   each thread: 96 coalesced bf16x8 loads (was 768 scalar loads), sO[d]
//   broadcast from LDS; 8-way cross-group reduce through dead sH buffer.
// ---------------------------------------------------------------------------
__global__ __launch_bounds__(1024) void attn_fused(
    const float* __restrict__ S, const float* __restrict__ colsum,
    const float* __restrict__ colsumsq, const ushort_t* __restrict__ h1t,
    const float* __restrict__ ln_g, const float* __restrict__ ln_b,
    const float* __restrict__ Wc, const ushort_t* __restrict__ Wout_b,
    float* __restrict__ out, int n, int Mn) {
    const int bq = blockIdx.x;
    const int bb = bq >> 6, qi = bq & 63;
    const int tid = threadIdx.x;
    const int lane = tid & 63, wv = tid >> 6;   // wv 0..15
    const int quad = lane >> 4, l15 = lane & 15;

    __shared__ ushort_t sW[9 * 1032];   // rows 0..7 = w[h], row 8 = zeros
    __shared__ ushort_t sH[64 * 264];   // H chunk; overlays: mu/rstd, rbuf
    __shared__ float sl[8], swmu[8];
    __shared__ float pm[16], pl[16], pwm[16];
    __shared__ float sA[512];
    __shared__ float sO[768];           // Wc-applied row (bf16-rounded)

    float* sMu = (float*)sH;            // [1024] (overwritten by chunk 0 stage)
    float* sRs = (float*)sH + 1024;     // [1024]

    // LN stats from column sums
    for (int i = tid; i < n; i += 1024) {
        const float cs = colsum[bb * n + i];
        const float cq = colsumsq[bb * n + i];
        const float m = cs * (1.0f / 4096.0f);
        sMu[i] = m;
        sRs[i] = rsqrtf(cq * (1.0f / 4096.0f) - m * m + 1e-5f);
    }
    // zero row 8 of sW
    for (int i = tid; i < 1032; i += 1024) sW[8 * 1032 + i] = 0;
    __syncthreads();

    // softmax: head h = wv>>1; each wave handles half of n.
    const int h = wv >> 1;
    const int half = wv & 1;
    const int nh = n >> 1;
    const int i0 = half * nh;
    const float* Sp = S + ((size_t)(bb * 8 + h) * 64 + qi) * n;
    {
        float m = -1e30f;
        for (int i = i0 + lane; i < i0 + nh; i += 64) m = fmaxf(m, Sp[i]);
#pragma unroll
        for (int off = 32; off > 0; off >>= 1) m = fmaxf(m, __shfl_down(m, off));
        if (lane == 0) pm[wv] = m;
    }
    __syncthreads();
    const float mh = fmaxf(pm[2 * h], pm[2 * h + 1]);
    {
        float l = 0.f, wm = 0.f;
        for (int i = i0 + lane; i < i0 + nh; i += 64) {
            const float e = expf(Sp[i] - mh);
            const float w = e * sRs[i];
            const ushort_t wb = f2b_rne(w);
            sW[h * 1032 + i] = wb;
            l += e;
            wm += b2f(wb) * sMu[i];
        }
#pragma unroll
        for (int off = 32; off > 0; off >>= 1) {
            l += __shfl_down(l, off);
            wm += __shfl_down(wm, off);
        }
        if (lane == 0) { pl[wv] = l; pwm[wv] = wm; }
    }
    __syncthreads();
    if (tid < 8) {
        sl[tid] = pl[2 * tid] + pl[2 * tid + 1];
        swmu[tid] = pwm[2 * tid] + pwm[2 * tid + 1];
    }

    // PV via MFMA: C[h(16)][r(64)] = w @ H^T, K = n in 256-chunks.
    const int mrow = (l15 < 8 ? l15 : 8) * 1032;
    f32x4 acc = {};
    const int nch = n >> 8;
    for (int ch = 0; ch < nch; ch++) {
        __syncthreads();  // chunk0: also protects sMu/sRs overlay + sW writes
        for (int g = tid; g < 2048; g += 1024) {
            const int row = g >> 5, seg = g & 31;
            *(bf16x8*)&sH[row * 264 + seg * 8] =
                *(const bf16x8*)&h1t[(size_t)(qi * 64 + row) * Mn + bb * n +
                                     ch * 256 + seg * 8];
        }
        __syncthreads();
        if (wv < 4) {
#pragma unroll
            for (int ks = 0; ks < 8; ks++) {
                const bf16x8 af = *(const bf16x8*)&sW[mrow + ch * 256 + ks * 32 + quad * 8];
                const bf16x8 bf = *(const bf16x8*)&sH[(wv * 16 + l15) * 264 + ks * 32 + quad * 8];
                acc = __builtin_amdgcn_mfma_f32_16x16x32_bf16(af, bf, acc, 0, 0, 0);
            }
        }
    }
    __syncthreads();

    // epilogue: wave j=wv<4 holds cols wv*16+l15, rows quad*4+r.
    if (wv < 4) {
#pragma unroll
        for (int r = 0; r < 4; r++) {
            const int hh = quad * 4 + r;
            if (hh < 8) {
                const int rr = wv * 16 + l15;
                const int c = qi * 64 + rr;
                sA[hh * 64 + rr] =
                    ln_g[c] * ((acc[r] - swmu[hh]) / sl[hh]) + ln_b[c];
            }
        }
    }
    __syncthreads();

    // Wc apply -> sO (bf16-rounded, fp32 storage for broadcast reads)
    for (int d = tid; d < 768; d += 1024) {
        const int hh = d / 96;
        const float* wp = Wc + (size_t)qi * 49152 + d;
        float a = 0.f;
#pragma unroll
        for (int r = 0; r < 64; r++) a += sA[hh * 64 + r] * wp[(size_t)r * 768];
        sO[d] = b2f(f2b_rne(a));
    }
    __syncthreads();

    // Row-grouped Wout matvec. Thread t<768: row-group r0 = t/96 handles
    // d in [r0*96, r0*96+96); dout slice c0 = (t%96)*8 .. +8.
    // Wout_b loads are 16B and coalesced along each row; sO[d] broadcasts.
    float* rbuf = (float*)sH;  // 8*768 floats = 24.6KB (sH dead after PV)
    if (tid < 768) {
        const int r0 = tid / 96;
        const int c0 = (tid % 96) * 8;
        const ushort_t* wp = Wout_b + (size_t)(r0 * 96) * 768 + c0;
        float acc8[8] = {};
#pragma unroll 4
        for (int s = 0; s < 96; s++) {
            const float sv = sO[r0 * 96 + s];
            const bf16x8 w8 = *(const bf16x8*)&wp[(size_t)s * 768];
#pragma unroll
            for (int j = 0; j < 8; j++) acc8[j] += sv * (float)w8[j];
        }
#pragma unroll
        for (int j = 0; j < 8; j++) rbuf[r0 * 768 + c0 + j] = acc8[j];
    }
    __syncthreads();
    if (tid < 768) {
        float s = 0.f;
#pragma unroll
        for (int g = 0; g < 8; g++) s += rbuf[g * 768 + tid];
        out[(size_t)bq * 768 + tid] = s;
    }
}

// ---------------------------------------------------------------------------
extern "C" void kernel_launch(void* const* d_in, const int* in_sizes, int n_in,
                              void* d_out, int out_size, void* d_ws, size_t ws_size,
                              hipStream_t stream) {
    const float* x       = (const float*)d_in[0];
    const float* context = (const float*)d_in[1];
    const float* Wq      = (const float*)d_in[2];
    const float* Wk      = (const float*)d_in[3];
    const float* Wv1     = (const float*)d_in[4];
    const float* ln_g    = (const float*)d_in[5];
    const float* ln_b    = (const float*)d_in[6];
    const float* Wc      = (const float*)d_in[7];
    const float* Wout    = (const float*)d_in[8];
    float* out = (float*)d_out;

    const int b = in_sizes[0] / (64 * 768);
    const int n = in_sizes[1] / (b * 768);
    const int M  = b * 64;     // 256
    const int Mn = b * n;      // 4096

    float* ws = (float*)d_ws;
    size_t off = 0;
    float* S       = ws + off;  off += (size_t)b * 8 * 64 * n;
    float* colsum  = ws + off;  off += (size_t)Mn;
    float* colsumsq= ws + off;  off += (size_t)Mn;

    ushort_t* us = (ushort_t*)(ws + off);
    size_t uo = 0;
    ushort_t* x_b    = us + uo;  uo += (size_t)M * 768;
    ushort_t* ctx_b  = us + uo;  uo += (size_t)Mn * 768;
    ushort_t* qb     = us + uo;  uo += (size_t)M * 768;
    ushort_t* kb     = us + uo;  uo += (size_t)Mn * 768;
    ushort_t* h1t    = us + uo;  uo += (size_t)Mn * 4096;   // [c][n_glob]
    ushort_t* Wq_t   = us + uo;  uo += (size_t)768 * 768;
    ushort_t* Wk_t   = us + uo;  uo += (size_t)768 * 768;
    ushort_t* Wv1_t  = us + uo;  uo += (size_t)4096 * 768;
    ushort_t* Wout_b = us + uo;  uo += (size_t)768 * 768;

    // 1. conversions + zero LN accumulators
    const int nb_x = (M * 768 / 4) / 256;
    const int nb_c = (Mn * 768 / 4) / 256;
    prep<<<nb_x + nb_c + 4800 + 8, 256, 0, stream>>>(
        x, context, Wq, Wk, Wv1, Wout, x_b, ctx_b, Wq_t, Wk_t, Wv1_t, Wout_b,
        colsum, b, n);

    // 2. q, k, h1^T GEMMs (BK=64, two stacked 32-slabs)
    const int tq = (M / 128) * 6, tk = (Mn / 128) * 6;
    const int th = (4096 / 128) * (Mn / 128);
    gemm3<<<tq + tk + th, 256, 0, stream>>>(x_b, ctx_b, Wq_t, Wk_t, Wv1_t,
                                            qb, kb, h1t, b, n);

    // 3. scores + LN column sums
    scores_stats<<<b * 8 * (n / 128) + 256, 256, 0, stream>>>(
        qb, kb, h1t, S, colsum, colsumsq, b, n, Mn);

    // 4. fused softmax + PV-MFMA + LN affine + Wc + row-grouped Wout matvec
    attn_fused<<<M, 1024, 0, stream>>>(S, colsum, colsumsq, h1t, ln_g, ln_b,
                                       Wc, Wout_b, out, n, Mn);
}